// Round 21
// baseline (380.655 us; speedup 1.0000x reference)
//
#include <hip/hip_runtime.h>
#include <math.h>

#define VOCAB 50257
#define EMB 1024
#define HD 1024
#define TRK 1024
#define LQ 256
#define BND 25
#define SENT 0xAAAAAAAAu

typedef __attribute__((ext_vector_type(8))) short short8v;
typedef __attribute__((ext_vector_type(4))) float float4v;

// ---------------- helpers ----------------
__device__ __forceinline__ float wred(float s){
  #pragma unroll
  for (int m = 32; m >= 1; m >>= 1) s += __shfl_xor(s, m, 64);
  return s;
}

// ---------------- K_clear: sentinel-fill hx ----------------
__global__ __launch_bounds__(256) void k_clear(uint4* __restrict__ p){
  p[blockIdx.x*256 + threadIdx.x] = make_uint4(SENT, SENT, SENT, SENT);
}

// ---------------- K_pre_keys: fused independent pre + keys ----------------
__global__ __launch_bounds__(256) void k_pre_keys(const float* __restrict__ Wih,
                                                  const float* __restrict__ qv,
                                                  const float* __restrict__ bih,
                                                  const int*   __restrict__ ta,
                                                  const float* __restrict__ emb,
                                                  const float* __restrict__ qw,
                                                  const float* __restrict__ Wk,
                                                  float* __restrict__ gib,
                                                  float* __restrict__ E,
                                                  float* __restrict__ part){
  __shared__ float qt[64*256];
  int b = blockIdx.x, tid = threadIdx.x;
  if (b < 768){
    int w = tid >> 6, lane = tid & 63;
    int row = b*4 + w;
    const float* a = Wih + (size_t)row*2048;
    float s = 0.f;
    #pragma unroll
    for (int e = 0; e < 4; e++){
      int k = e*256 + lane*4;
      float4 av = *(const float4*)(a + k);
      float4 qr = *(const float4*)(qv + k);
      s += av.x*qr.x + av.y*qr.y + av.z*qr.z + av.w*qr.w;
    }
    s = wred(s);
    if (lane == 0) gib[row] = s + bih[row];
    return;
  }
  if (b < 868){
    int g = (b - 768)*256 + tid;
    int t = g >> 10, i = g & 1023;
    int idx = (t == 0) ? 0 : ta[t-1];
    E[g] = emb[(size_t)idx*EMB + i];
    return;
  }
  int b2 = b - 868;
  int jb = b2 & 63;
  int ks = b2 >> 6;
  int l = tid;
  float acc[16];
  #pragma unroll
  for (int j = 0; j < 16; j++) acc[j] = 0.f;

  for (int kt = 0; kt < 4; kt++){
    int kb = ks*256 + kt*64;
    __syncthreads();
    #pragma unroll
    for (int p = 0; p < 16; p++){
      int fidx = (p*256 + tid)*4;
      int kk = fidx & 63, ll = fidx >> 6;
      float4 v = *(const float4*)(qw + (size_t)ll*1024 + kb + kk);
      qt[(kk+0)*256 + (ll ^ ((kk+0)&31))] = v.x;
      qt[(kk+1)*256 + (ll ^ ((kk+1)&31))] = v.y;
      qt[(kk+2)*256 + (ll ^ ((kk+2)&31))] = v.z;
      qt[(kk+3)*256 + (ll ^ ((kk+3)&31))] = v.w;
    }
    __syncthreads();
    #pragma unroll
    for (int s = 0; s < 4; s++){
      float qr[16];
      #pragma unroll
      for (int q = 0; q < 16; q++){
        int k = s*16 + q;
        qr[q] = qt[k*256 + (l ^ (k&31))];
      }
      #pragma unroll
      for (int j = 0; j < 16; j++){
        const float* wr = Wk + (size_t)(jb*16 + j)*1024 + kb + s*16;
        #pragma unroll
        for (int q4 = 0; q4 < 4; q4++){
          float4 wv = *(const float4*)(wr + q4*4);
          acc[j] += qr[q4*4+0]*wv.x + qr[q4*4+1]*wv.y
                  + qr[q4*4+2]*wv.z + qr[q4*4+3]*wv.w;
        }
      }
    }
  }
  #pragma unroll
  for (int j = 0; j < 16; j++)
    part[((size_t)ks*1024 + jb*16 + j)*256 + l] = acc[j];
}

// ---------------- K_gemm_s2: skinny GEMM; optional bf16 hi/lo emit ----------------
template<int K, int NCH>
__global__ __launch_bounds__(256) void k_gemm_s2(const float* __restrict__ A, int lda,
                                                 const float* __restrict__ B, int ldb,
                                                 const float* __restrict__ bias,
                                                 float* __restrict__ C,
                                                 int R, int N, int act,
                                                 short* __restrict__ Bhi,
                                                 short* __restrict__ Blo){
  __shared__ float Bl[NCH*K];
  constexpr int KD4 = K/4;
  int tid = threadIdx.x, w = tid >> 6, lane = tid & 63;
  int row = blockIdx.x*4 + w;
  const float* a = A + (size_t)row*lda;
  float4 ar[K/256];
  #pragma unroll
  for (int e = 0; e < K/256; e++)
    ar[e] = *(const float4*)(a + e*256 + lane*4);
  float bs = bias[row];
  for (int c0 = 0; c0 < N; c0 += NCH){
    int nt = min(NCH, N - c0);
    __syncthreads();
    int total = nt*KD4;
    for (int i = tid; i < total; i += 256){
      int j = i/KD4, kk = i - j*KD4;
      *(float4*)&Bl[j*K + kk*4] = *(const float4*)(B + (size_t)(c0+j)*ldb + kk*4);
    }
    __syncthreads();
    for (int j = 0; j < nt; j++){
      float s = 0.f;
      #pragma unroll
      for (int e = 0; e < K/256; e++){
        float4 bv = *(const float4*)&Bl[j*K + e*256 + lane*4];
        s += ar[e].x*bv.x + ar[e].y*bv.y + ar[e].z*bv.z + ar[e].w*bv.w;
      }
      s = wred(s);
      if (lane == 0){
        float v = s + bs;
        if (act) v = tanhf(v);
        C[(size_t)(c0+j)*R + row] = v;
        if (Bhi){
          size_t idx = (size_t)(c0+j)*R + row;
          unsigned bits = __float_as_uint(v);
          Bhi[idx] = (short)(bits >> 16);
          float lo = v - __uint_as_float(bits & 0xFFFF0000u);
          Blo[idx] = (short)(__float_as_uint(lo) >> 16);
        }
      }
    }
  }
}

// ---------------- K_gru8: 25 steps; 128 blocks x 512 thr; 2-wave poll + backoff ----------------
__global__ __launch_bounds__(512, 1) void k_gru8(const float* __restrict__ Whh,
                                                 const float* __restrict__ bhh,
                                                 const float* __restrict__ gi,
                                                 const float* __restrict__ dv,
                                                 float* __restrict__ HC,
                                                 unsigned* __restrict__ hxu){
  __shared__ float Wl[24][1024];
  __shared__ float hbuf[1024];
  __shared__ float sres[24];
  int tid = threadIdx.x, w = tid >> 6, lane = tid & 63;
  int b = blockIdx.x;
  for (int i = tid; i < 6144; i += 512){
    int r = i >> 8, c = (i & 255)*4;
    int g = r >> 3, s = r & 7;
    *(float4*)&Wl[r][c] = *(const float4*)(Whh + (size_t)(g*1024 + b*8 + s)*1024 + c);
  }
  if (tid < 256)
    *(float4*)&hbuf[tid*4] = *(const float4*)(dv + tid*4);
  __syncthreads();

  for (int t = 0; t < BND; t++){
    float g0=0,g1=0,g2=0,bb0=0,bb1=0,bb2=0,hpown=0;
    if (tid < 8){
      int i = b*8 + tid;
      const float* gg = gi + (size_t)t*3072;
      g0 = gg[i]; g1 = gg[1024+i]; g2 = gg[2048+i];
      bb0 = bhh[i]; bb1 = bhh[1024+i]; bb2 = bhh[2048+i];
      hpown = hbuf[i];
    }
    float hv[16];
    #pragma unroll
    for (int e = 0; e < 4; e++){
      float4 v = *(const float4*)&hbuf[e*256 + lane*4];
      hv[e*4]=v.x; hv[e*4+1]=v.y; hv[e*4+2]=v.z; hv[e*4+3]=v.w;
    }
    #pragma unroll
    for (int j = 0; j < 3; j++){
      int r = w*3 + j;
      float a = 0.f;
      #pragma unroll
      for (int e = 0; e < 4; e++){
        float4 v = *(const float4*)&Wl[r][e*256 + lane*4];
        a += v.x*hv[e*4] + v.y*hv[e*4+1] + v.z*hv[e*4+2] + v.w*hv[e*4+3];
      }
      a = wred(a);
      if (lane == 0) sres[r] = a;
    }
    __syncthreads();
    if (tid < 8){
      int i = b*8 + tid;
      float ghr = sres[tid]      + bb0;
      float ghz = sres[8  + tid] + bb1;
      float ghn = sres[16 + tid] + bb2;
      float rr = 1.f/(1.f + expf(-(g0 + ghr)));
      float zz = 1.f/(1.f + expf(-(g1 + ghz)));
      float nn = tanhf(g2 + rr*ghn);
      float hnew = (1.f - zz)*nn + zz*hpown;
      HC[(size_t)t*2048 + i] = hnew;
      if (t < BND-1){
        union { float f; unsigned u; } cv; cv.f = hnew;
        if (cv.u == SENT) cv.u ^= 1u;
        __hip_atomic_store(hxu + (size_t)t*2048 + b*16 + tid, cv.u,
                           __ATOMIC_RELAXED, __HIP_MEMORY_SCOPE_AGENT);
      }
    }
    if (t == BND-1) break;
    if (w < 2){
      int blk = w*64 + lane;
      const unsigned* bp = hxu + (size_t)t*2048 + blk*16;
      unsigned d[8];
      for (;;){
        bool ok = true;
        #pragma unroll
        for (int j = 0; j < 8; j++){
          d[j] = __hip_atomic_load(bp + j, __ATOMIC_RELAXED, __HIP_MEMORY_SCOPE_AGENT);
          ok = ok && (d[j] != SENT);
        }
        if (ok) break;
        __builtin_amdgcn_s_sleep(1);
      }
      #pragma unroll
      for (int j = 0; j < 8; j++)
        hbuf[blk*8 + j] = __uint_as_float(d[j]);
    }
    __syncthreads();
  }
}

// ---------------- K_attn1: e partials; folds keys 4-way reduction ----------------
__global__ __launch_bounds__(256) void k_attn1(const float* __restrict__ part,
                                               const float* __restrict__ bk,
                                               const float* __restrict__ Qt,
                                               const float* __restrict__ av,
                                               float* __restrict__ epart){
  int t = blockIdx.x, jc = blockIdx.y;
  int l = threadIdx.x;
  const float* q = Qt + (size_t)t*1024;
  int j0 = jc*32;
  float acc = 0.f;
  #pragma unroll
  for (int u = 0; u < 8; u++){
    #pragma unroll
    for (int v = 0; v < 4; v++){
      int j = j0 + u*4 + v;
      float kv = part[(size_t)j*256 + l]
               + part[(size_t)(1024+j)*256 + l]
               + part[(size_t)(2048+j)*256 + l]
               + part[(size_t)(3072+j)*256 + l]
               + bk[j];
      acc += tanhf(kv + q[j]) * av[j];
    }
  }
  epart[((size_t)t*32 + jc)*256 + l] = acc;
}

// ---------------- K_attn2: softmax over l + ctx = w @ qw ----------------
__global__ __launch_bounds__(256) void k_attn2(const float* __restrict__ epart,
                                               const float* __restrict__ qw,
                                               float* __restrict__ HC){
  __shared__ float red[256];
  __shared__ float sw[256];
  int t = blockIdx.x, tid = threadIdx.x;
  float e = 0.f;
  for (int jc = 0; jc < 32; jc++) e += epart[((size_t)t*32 + jc)*256 + tid];
  red[tid] = e; __syncthreads();
  for (int s = 128; s > 0; s >>= 1){
    if (tid < s) red[tid] = fmaxf(red[tid], red[tid+s]);
    __syncthreads();
  }
  float m = red[0]; __syncthreads();
  float wv = expf(e - m);
  red[tid] = wv; __syncthreads();
  for (int s = 128; s > 0; s >>= 1){
    if (tid < s) red[tid] += red[tid+s];
    __syncthreads();
  }
  float inv = 1.f/red[0];
  sw[tid] = wv*inv; __syncthreads();
  float4 c = make_float4(0.f,0.f,0.f,0.f);
  const float* qp = qw + tid*4;
  for (int ll = 0; ll < 256; ll++){
    float wl = sw[ll];
    float4 v = *(const float4*)(qp + (size_t)ll*1024);
    c.x += wl*v.x; c.y += wl*v.y; c.z += wl*v.z; c.w += wl*v.w;
  }
  *(float4*)(HC + (size_t)t*2048 + 1024 + tid*4) = c;
}

// ---------------- K_gemm_mfma4: 50257x1024 @ 1024x25, k-split x2, 786 blocks ----------------
// LDS-free 3-pass bf16-split MFMA, 32 VGPR -> occupancy purely grid-driven.
// 786 blocks = 393 row-groups (128 rows) x 2 k-halves -> 3144 waves (~3/SIMD,
// mfma3 had 1.5). A traffic unchanged (waves read disjoint k-halves); B loads
// halve per wave. Partials: kh=0 -> P0 (dead part/ep alias), kh=1 -> C;
// lstat/lsub2 fold P0+P1+bias (+10MB streaming ~ 3us, proven in round 13).
__global__ __launch_bounds__(256, 1) void k_gemm_mfma4(const float* __restrict__ A,
                                                       const short* __restrict__ Bhi,
                                                       const short* __restrict__ Blo,
                                                       float* __restrict__ P0,
                                                       float* __restrict__ P1){
  int tid = threadIdx.x, lane = tid & 63, w = tid >> 6;
  int rlo = lane & 15, kg = lane >> 4;
  int kh = blockIdx.x & 1;
  int R0 = (blockIdx.x >> 1)*128 + w*32;
  float* P = kh ? P1 : P0;
  int kbase = kh*512 + kg*8;

  const float* ap[2];
  #pragma unroll
  for (int rt = 0; rt < 2; rt++){
    int row = R0 + rt*16 + rlo;
    if (row >= VOCAB) row = VOCAB-1;
    ap[rt] = A + (size_t)row*1024 + kbase;
  }
  int t0 = rlo;
  int t1 = 16 + rlo; if (t1 > 24) t1 = 24;
  const short* bh0 = Bhi + t0*1024 + kbase;
  const short* bl0 = Blo + t0*1024 + kbase;
  const short* bh1 = Bhi + t1*1024 + kbase;
  const short* bl1 = Blo + t1*1024 + kbase;

  float4v acc[2][2];
  #pragma unroll
  for (int rt = 0; rt < 2; rt++)
    #pragma unroll
    for (int ct = 0; ct < 2; ct++)
      acc[rt][ct] = (float4v){0.f,0.f,0.f,0.f};

  #pragma unroll 4
  for (int s = 0; s < 16; s++){
    int ko = s*32;
    short8v bh[2], bl[2];
    bh[0] = *(const short8v*)(bh0 + ko);
    bl[0] = *(const short8v*)(bl0 + ko);
    bh[1] = *(const short8v*)(bh1 + ko);
    bl[1] = *(const short8v*)(bl1 + ko);
    #pragma unroll
    for (int rt = 0; rt < 2; rt++){
      float4 a0 = *(const float4*)(ap[rt] + ko);
      float4 a1 = *(const float4*)(ap[rt] + ko + 4);
      float av[8] = {a0.x,a0.y,a0.z,a0.w,a1.x,a1.y,a1.z,a1.w};
      short8v ah, al;
      #pragma unroll
      for (int j = 0; j < 8; j++){
        unsigned bits = __float_as_uint(av[j]);
        ah[j] = (short)(bits >> 16);
        float lo = av[j] - __uint_as_float(bits & 0xFFFF0000u);
        al[j] = (short)(__float_as_uint(lo) >> 16);
      }
      #pragma unroll
      for (int ct = 0; ct < 2; ct++){
        acc[rt][ct] = __builtin_amdgcn_mfma_f32_16x16x32_bf16(ah, bh[ct], acc[rt][ct], 0, 0, 0);
        acc[rt][ct] = __builtin_amdgcn_mfma_f32_16x16x32_bf16(ah, bl[ct], acc[rt][ct], 0, 0, 0);
        acc[rt][ct] = __builtin_amdgcn_mfma_f32_16x16x32_bf16(al, bh[ct], acc[rt][ct], 0, 0, 0);
      }
    }
  }

  #pragma unroll
  for (int rt = 0; rt < 2; rt++){
    #pragma unroll
    for (int ct = 0; ct < 2; ct++){
      int t = ct*16 + rlo;
      if (t >= 25) continue;
      #pragma unroll
      for (int reg = 0; reg < 4; reg++){
        int rout = R0 + rt*16 + kg*4 + reg;
        if (rout < VOCAB)
          P[(size_t)t*VOCAB + rout] = acc[rt][ct][reg];
      }
    }
  }
}

// ---------------- K_lstat: stats over s = P0+P1+bias ----------------
__global__ __launch_bounds__(256) void k_lstat(const float* __restrict__ P0,
                                               const float* __restrict__ P1,
                                               const float* __restrict__ ob,
                                               float* __restrict__ pm,
                                               float* __restrict__ ps,
                                               int*   __restrict__ pa){
  __shared__ float sm[256], ss[256];
  __shared__ int   sa[256];
  int t = blockIdx.x, c = blockIdx.y, tid = threadIdx.x;
  int r0 = c*6283, r1 = min(r0 + 6283, VOCAB);
  const float* p0 = P0 + (size_t)t*VOCAB;
  const float* p1 = P1 + (size_t)t*VOCAB;
  float m = -3.4e38f, s = 0.f; int arg = r0;
  for (int r = r0 + tid; r < r1; r += 256){
    float x = p0[r] + p1[r] + ob[r];
    if (x > m){ s = s*expf(m - x) + 1.f; m = x; arg = r; }
    else       s += expf(x - m);
  }
  sm[tid] = m; ss[tid] = s; sa[tid] = arg; __syncthreads();
  for (int st = 128; st > 0; st >>= 1){
    if (tid < st){
      float m1 = sm[tid], s1 = ss[tid]; int a1 = sa[tid];
      float m2 = sm[tid+st], s2 = ss[tid+st]; int a2 = sa[tid+st];
      if (m2 > m1){ sm[tid] = m2; ss[tid] = s2 + s1*expf(m1 - m2); sa[tid] = a2; }
      else if (m2 == m1){ ss[tid] = s1 + s2; sa[tid] = min(a1, a2); }
      else { ss[tid] = s1 + s2*expf(m2 - m1); }
    }
    __syncthreads();
  }
  if (tid == 0){ pm[t*8 + c] = sm[0]; ps[t*8 + c] = ss[0]; pa[t*8 + c] = sa[0]; }
}

// ---------------- K_lsub2: C = P0 + C + bias - Lg[t]; folds lfin ----------------
__global__ __launch_bounds__(256) void k_lsub2(const float* __restrict__ P0,
                                               float* __restrict__ C,
                                               const float* __restrict__ ob,
                                               const float* __restrict__ pm,
                                               const float* __restrict__ ps,
                                               const int* __restrict__ pa,
                                               float* __restrict__ out){
  int t = blockIdx.y;
  float M = pm[t*8], S = ps[t*8]; int A = pa[t*8];
  #pragma unroll
  for (int c = 1; c < 8; c++){
    float m2 = pm[t*8+c], s2 = ps[t*8+c]; int a2 = pa[t*8+c];
    if (m2 > M){ S = s2 + S*expf(M - m2); M = m2; A = a2; }
    else if (m2 == M){ S += s2; A = min(A, a2); }
    else S += s2*expf(m2 - M);
  }
  float Lg = logf(S) + M;
  int r = blockIdx.x*256 + threadIdx.x;
  if (r < VOCAB){
    size_t idx = (size_t)t*VOCAB + r;
    C[idx] = P0[idx] + C[idx] + ob[r] - Lg;
  }
  if (blockIdx.x == 0 && threadIdx.x == 0) out[t] = (float)A;
}

// ---------------- launch ----------------
extern "C" void kernel_launch(void* const* d_in, const int* in_sizes, int n_in,
                              void* d_out, int out_size, void* d_ws, size_t ws_size,
                              hipStream_t stream){
  const float* qw  = (const float*)d_in[0];
  const float* qv  = (const float*)d_in[1];
  const float* dv  = (const float*)d_in[2];
  const int*   ta  = (const int*)d_in[3];
  const float* emb = (const float*)d_in[4];
  const float* Wih = (const float*)d_in[5];
  const float* Whh = (const float*)d_in[6];
  const float* bih = (const float*)d_in[7];
  const float* bhh = (const float*)d_in[8];
  const float* Wq  = (const float*)d_in[9];
  const float* bq  = (const float*)d_in[10];
  const float* Wk  = (const float*)d_in[11];
  const float* bk  = (const float*)d_in[12];
  const float* av  = (const float*)d_in[13];
  const float* cW  = (const float*)d_in[14];
  const float* cb  = (const float*)d_in[15];
  const float* oW  = (const float*)d_in[16];
  const float* ob  = (const float*)d_in[17];
  float* out = (float*)d_out;
  float* ws  = (float*)d_ws;

  float* part  = ws;                 // 1048576 (live until attn1)
  float* ep    = ws + 1048576;       // 204800 (live until attn2)
  float* P0    = ws;                 // 1256425 floats (aliases part+ep+gap; mfma4 phase)
  float* E     = ws + 1310720;       // 25600
  float* gib   = ws + 1336320;       // 3072
  float* gi    = ws + 1339392;       // 76800
  float* HC    = ws + 1416192;       // 51200
  float* Qt    = ws + 1467392;       // 25600
  float* VEC   = ws + 1492992;       // 25600
  unsigned* hx = (unsigned*)(ws + 1518592); // 51200
  float* pm    = ws + 1569792;       // 200
  float* ps    = ws + 1570048;       // 200
  int*   pa    = (int*)(ws + 1570304); // 200
  short* Bhi   = (short*)(ws + 1570816); // 25600 shorts
  short* Blo   = (short*)(ws + 1583616); // 25600 shorts

  k_clear<<<50, 256, 0, stream>>>((uint4*)hx);
  k_pre_keys<<<1124, 256, 0, stream>>>(Wih, qv, bih, ta, emb, qw, Wk, gib, E, part);
  k_gemm_s2<1024,16><<<768, 256, 0, stream>>>(Wih + 1024, 2048, E, 1024, gib, gi, 3072, 25, 0, nullptr, nullptr);
  k_gru8<<<128, 512, 0, stream>>>(Whh, bhh, gi, dv, HC, hx);
  k_gemm_s2<1024,16><<<256, 256, 0, stream>>>(Wq, 1024, HC, 2048, bq, Qt, 1024, 25, 0, nullptr, nullptr);
  k_attn1<<<dim3(25,32), 256, 0, stream>>>(part, bk, Qt, av, ep);
  k_attn2<<<25, 256, 0, stream>>>(ep, qw, HC);
  k_gemm_s2<2048,8><<<256, 256, 0, stream>>>(cW, 2048, HC, 2048, cb, VEC, 1024, 25, 1, Bhi, Blo);
  k_gemm_mfma4<<<786, 256, 0, stream>>>(oW, Bhi, Blo, P0, out + 25);
  k_lstat<<<dim3(25,8), 256, 0, stream>>>(P0, out + 25, ob, pm, ps, pa);
  k_lsub2<<<dim3(197,25), 256, 0, stream>>>(P0, out + 25, ob, pm, ps, pa, out);
}

// Round 22
// 362.955 us; speedup vs baseline: 1.0488x; 1.0488x over previous
//
#include <hip/hip_runtime.h>
#include <math.h>

#define VOCAB 50257
#define EMB 1024
#define HD 1024
#define TRK 1024
#define LQ 256
#define BND 25
#define SENT 0xAAAAAAAAu

typedef __attribute__((ext_vector_type(8))) short short8v;
typedef __attribute__((ext_vector_type(4))) float float4v;

// ---------------- helpers ----------------
__device__ __forceinline__ float wred(float s){
  #pragma unroll
  for (int m = 32; m >= 1; m >>= 1) s += __shfl_xor(s, m, 64);
  return s;
}

// ---------------- K_pre_keys: fused pre + keys + hx sentinel clear ----------------
// b<768: gi_base wave-dots; 768<=b<868: emb gather; 868<=b<1124: keys partials;
// b>=1124: hx sentinel fill (50 blocks; consumed by gru8 two launches later).
__global__ __launch_bounds__(256) void k_pre_keys(const float* __restrict__ Wih,
                                                  const float* __restrict__ qv,
                                                  const float* __restrict__ bih,
                                                  const int*   __restrict__ ta,
                                                  const float* __restrict__ emb,
                                                  const float* __restrict__ qw,
                                                  const float* __restrict__ Wk,
                                                  float* __restrict__ gib,
                                                  float* __restrict__ E,
                                                  float* __restrict__ part,
                                                  uint4* __restrict__ hxc){
  __shared__ float qt[64*256];
  int b = blockIdx.x, tid = threadIdx.x;
  if (b >= 1124){
    hxc[(b - 1124)*256 + tid] = make_uint4(SENT, SENT, SENT, SENT);
    return;
  }
  if (b < 768){
    int w = tid >> 6, lane = tid & 63;
    int row = b*4 + w;
    const float* a = Wih + (size_t)row*2048;
    float s = 0.f;
    #pragma unroll
    for (int e = 0; e < 4; e++){
      int k = e*256 + lane*4;
      float4 av = *(const float4*)(a + k);
      float4 qr = *(const float4*)(qv + k);
      s += av.x*qr.x + av.y*qr.y + av.z*qr.z + av.w*qr.w;
    }
    s = wred(s);
    if (lane == 0) gib[row] = s + bih[row];
    return;
  }
  if (b < 868){
    int g = (b - 768)*256 + tid;
    int t = g >> 10, i = g & 1023;
    int idx = (t == 0) ? 0 : ta[t-1];
    E[g] = emb[(size_t)idx*EMB + i];
    return;
  }
  int b2 = b - 868;
  int jb = b2 & 63;
  int ks = b2 >> 6;
  int l = tid;
  float acc[16];
  #pragma unroll
  for (int j = 0; j < 16; j++) acc[j] = 0.f;

  for (int kt = 0; kt < 4; kt++){
    int kb = ks*256 + kt*64;
    __syncthreads();
    #pragma unroll
    for (int p = 0; p < 16; p++){
      int fidx = (p*256 + tid)*4;
      int kk = fidx & 63, ll = fidx >> 6;
      float4 v = *(const float4*)(qw + (size_t)ll*1024 + kb + kk);
      qt[(kk+0)*256 + (ll ^ ((kk+0)&31))] = v.x;
      qt[(kk+1)*256 + (ll ^ ((kk+1)&31))] = v.y;
      qt[(kk+2)*256 + (ll ^ ((kk+2)&31))] = v.z;
      qt[(kk+3)*256 + (ll ^ ((kk+3)&31))] = v.w;
    }
    __syncthreads();
    #pragma unroll
    for (int s = 0; s < 4; s++){
      float qr[16];
      #pragma unroll
      for (int q = 0; q < 16; q++){
        int k = s*16 + q;
        qr[q] = qt[k*256 + (l ^ (k&31))];
      }
      #pragma unroll
      for (int j = 0; j < 16; j++){
        const float* wr = Wk + (size_t)(jb*16 + j)*1024 + kb + s*16;
        #pragma unroll
        for (int q4 = 0; q4 < 4; q4++){
          float4 wv = *(const float4*)(wr + q4*4);
          acc[j] += qr[q4*4+0]*wv.x + qr[q4*4+1]*wv.y
                  + qr[q4*4+2]*wv.z + qr[q4*4+3]*wv.w;
        }
      }
    }
  }
  #pragma unroll
  for (int j = 0; j < 16; j++)
    part[((size_t)ks*1024 + jb*16 + j)*256 + l] = acc[j];
}

// ---------------- K_gemm_s2: skinny GEMM; optional bf16 hi/lo emit ----------------
template<int K, int NCH>
__global__ __launch_bounds__(256) void k_gemm_s2(const float* __restrict__ A, int lda,
                                                 const float* __restrict__ B, int ldb,
                                                 const float* __restrict__ bias,
                                                 float* __restrict__ C,
                                                 int R, int N, int act,
                                                 short* __restrict__ Bhi,
                                                 short* __restrict__ Blo){
  __shared__ float Bl[NCH*K];
  constexpr int KD4 = K/4;
  int tid = threadIdx.x, w = tid >> 6, lane = tid & 63;
  int row = blockIdx.x*4 + w;
  const float* a = A + (size_t)row*lda;
  float4 ar[K/256];
  #pragma unroll
  for (int e = 0; e < K/256; e++)
    ar[e] = *(const float4*)(a + e*256 + lane*4);
  float bs = bias[row];
  for (int c0 = 0; c0 < N; c0 += NCH){
    int nt = min(NCH, N - c0);
    __syncthreads();
    int total = nt*KD4;
    for (int i = tid; i < total; i += 256){
      int j = i/KD4, kk = i - j*KD4;
      *(float4*)&Bl[j*K + kk*4] = *(const float4*)(B + (size_t)(c0+j)*ldb + kk*4);
    }
    __syncthreads();
    for (int j = 0; j < nt; j++){
      float s = 0.f;
      #pragma unroll
      for (int e = 0; e < K/256; e++){
        float4 bv = *(const float4*)&Bl[j*K + e*256 + lane*4];
        s += ar[e].x*bv.x + ar[e].y*bv.y + ar[e].z*bv.z + ar[e].w*bv.w;
      }
      s = wred(s);
      if (lane == 0){
        float v = s + bs;
        if (act) v = tanhf(v);
        C[(size_t)(c0+j)*R + row] = v;
        if (Bhi){
          size_t idx = (size_t)(c0+j)*R + row;
          unsigned bits = __float_as_uint(v);
          Bhi[idx] = (short)(bits >> 16);
          float lo = v - __uint_as_float(bits & 0xFFFF0000u);
          Blo[idx] = (short)(__float_as_uint(lo) >> 16);
        }
      }
    }
  }
}

// ---------------- K_gru8: 25 steps; 128 blocks x 512 thr; 2-wave poll + backoff ----------------
__global__ __launch_bounds__(512, 1) void k_gru8(const float* __restrict__ Whh,
                                                 const float* __restrict__ bhh,
                                                 const float* __restrict__ gi,
                                                 const float* __restrict__ dv,
                                                 float* __restrict__ HC,
                                                 unsigned* __restrict__ hxu){
  __shared__ float Wl[24][1024];
  __shared__ float hbuf[1024];
  __shared__ float sres[24];
  int tid = threadIdx.x, w = tid >> 6, lane = tid & 63;
  int b = blockIdx.x;
  for (int i = tid; i < 6144; i += 512){
    int r = i >> 8, c = (i & 255)*4;
    int g = r >> 3, s = r & 7;
    *(float4*)&Wl[r][c] = *(const float4*)(Whh + (size_t)(g*1024 + b*8 + s)*1024 + c);
  }
  if (tid < 256)
    *(float4*)&hbuf[tid*4] = *(const float4*)(dv + tid*4);
  __syncthreads();

  for (int t = 0; t < BND; t++){
    float g0=0,g1=0,g2=0,bb0=0,bb1=0,bb2=0,hpown=0;
    if (tid < 8){
      int i = b*8 + tid;
      const float* gg = gi + (size_t)t*3072;
      g0 = gg[i]; g1 = gg[1024+i]; g2 = gg[2048+i];
      bb0 = bhh[i]; bb1 = bhh[1024+i]; bb2 = bhh[2048+i];
      hpown = hbuf[i];
    }
    float hv[16];
    #pragma unroll
    for (int e = 0; e < 4; e++){
      float4 v = *(const float4*)&hbuf[e*256 + lane*4];
      hv[e*4]=v.x; hv[e*4+1]=v.y; hv[e*4+2]=v.z; hv[e*4+3]=v.w;
    }
    #pragma unroll
    for (int j = 0; j < 3; j++){
      int r = w*3 + j;
      float a = 0.f;
      #pragma unroll
      for (int e = 0; e < 4; e++){
        float4 v = *(const float4*)&Wl[r][e*256 + lane*4];
        a += v.x*hv[e*4] + v.y*hv[e*4+1] + v.z*hv[e*4+2] + v.w*hv[e*4+3];
      }
      a = wred(a);
      if (lane == 0) sres[r] = a;
    }
    __syncthreads();
    if (tid < 8){
      int i = b*8 + tid;
      float ghr = sres[tid]      + bb0;
      float ghz = sres[8  + tid] + bb1;
      float ghn = sres[16 + tid] + bb2;
      float rr = 1.f/(1.f + expf(-(g0 + ghr)));
      float zz = 1.f/(1.f + expf(-(g1 + ghz)));
      float nn = tanhf(g2 + rr*ghn);
      float hnew = (1.f - zz)*nn + zz*hpown;
      HC[(size_t)t*2048 + i] = hnew;
      if (t < BND-1){
        union { float f; unsigned u; } cv; cv.f = hnew;
        if (cv.u == SENT) cv.u ^= 1u;
        __hip_atomic_store(hxu + (size_t)t*2048 + b*16 + tid, cv.u,
                           __ATOMIC_RELAXED, __HIP_MEMORY_SCOPE_AGENT);
      }
    }
    if (t == BND-1) break;
    if (w < 2){
      int blk = w*64 + lane;
      const unsigned* bp = hxu + (size_t)t*2048 + blk*16;
      unsigned d[8];
      for (;;){
        bool ok = true;
        #pragma unroll
        for (int j = 0; j < 8; j++){
          d[j] = __hip_atomic_load(bp + j, __ATOMIC_RELAXED, __HIP_MEMORY_SCOPE_AGENT);
          ok = ok && (d[j] != SENT);
        }
        if (ok) break;
        __builtin_amdgcn_s_sleep(1);
      }
      #pragma unroll
      for (int j = 0; j < 8; j++)
        hbuf[blk*8 + j] = __uint_as_float(d[j]);
    }
    __syncthreads();
  }
}

// ---------------- K_attn1: e partials; folds keys 4-way reduction ----------------
__global__ __launch_bounds__(256) void k_attn1(const float* __restrict__ part,
                                               const float* __restrict__ bk,
                                               const float* __restrict__ Qt,
                                               const float* __restrict__ av,
                                               float* __restrict__ epart){
  int t = blockIdx.x, jc = blockIdx.y;
  int l = threadIdx.x;
  const float* q = Qt + (size_t)t*1024;
  int j0 = jc*32;
  float acc = 0.f;
  #pragma unroll
  for (int u = 0; u < 8; u++){
    #pragma unroll
    for (int v = 0; v < 4; v++){
      int j = j0 + u*4 + v;
      float kv = part[(size_t)j*256 + l]
               + part[(size_t)(1024+j)*256 + l]
               + part[(size_t)(2048+j)*256 + l]
               + part[(size_t)(3072+j)*256 + l]
               + bk[j];
      acc += tanhf(kv + q[j]) * av[j];
    }
  }
  epart[((size_t)t*32 + jc)*256 + l] = acc;
}

// ---------------- K_attn2: softmax + ctx; grid (25,2) halves serial ctx loop ----------------
__global__ __launch_bounds__(256) void k_attn2(const float* __restrict__ epart,
                                               const float* __restrict__ qw,
                                               float* __restrict__ HC){
  __shared__ float red[256];
  __shared__ float sw[256];
  int t = blockIdx.x, half = blockIdx.y, tid = threadIdx.x;
  float e = 0.f;
  for (int jc = 0; jc < 32; jc++) e += epart[((size_t)t*32 + jc)*256 + tid];
  red[tid] = e; __syncthreads();
  for (int s = 128; s > 0; s >>= 1){
    if (tid < s) red[tid] = fmaxf(red[tid], red[tid+s]);
    __syncthreads();
  }
  float m = red[0]; __syncthreads();
  float wv = expf(e - m);
  red[tid] = wv; __syncthreads();
  for (int s = 128; s > 0; s >>= 1){
    if (tid < s) red[tid] += red[tid+s];
    __syncthreads();
  }
  float inv = 1.f/red[0];
  sw[tid] = wv*inv; __syncthreads();
  float2 c = make_float2(0.f, 0.f);
  const float* qp = qw + half*512 + tid*2;
  for (int ll = 0; ll < 256; ll++){
    float wl = sw[ll];
    float2 v = *(const float2*)(qp + (size_t)ll*1024);
    c.x += wl*v.x; c.y += wl*v.y;
  }
  *(float2*)(HC + (size_t)t*2048 + 1024 + half*512 + tid*2) = c;
}

// ---------------- K_gemm_mfma3: 50257x1024 @ 1024x25, r=2 rowtiles, 393 blocks ----------------
// (round-20 proven config) LDS-free 3-pass bf16-split MFMA; 393 blocks x 4 waves.
__global__ __launch_bounds__(256, 1) void k_gemm_mfma3(const float* __restrict__ A,
                                                       const short* __restrict__ Bhi,
                                                       const short* __restrict__ Blo,
                                                       const float* __restrict__ bias,
                                                       float* __restrict__ C){
  int tid = threadIdx.x, lane = tid & 63, w = tid >> 6;
  int rlo = lane & 15, kg = lane >> 4;
  int R0 = blockIdx.x*128 + w*32;

  const float* ap[2];
  #pragma unroll
  for (int rt = 0; rt < 2; rt++){
    int row = R0 + rt*16 + rlo;
    if (row >= VOCAB) row = VOCAB-1;
    ap[rt] = A + (size_t)row*1024 + kg*8;
  }
  int t0 = rlo;
  int t1 = 16 + rlo; if (t1 > 24) t1 = 24;
  const short* bh0 = Bhi + t0*1024 + kg*8;
  const short* bl0 = Blo + t0*1024 + kg*8;
  const short* bh1 = Bhi + t1*1024 + kg*8;
  const short* bl1 = Blo + t1*1024 + kg*8;

  float4v acc[2][2];
  #pragma unroll
  for (int rt = 0; rt < 2; rt++)
    #pragma unroll
    for (int ct = 0; ct < 2; ct++)
      acc[rt][ct] = (float4v){0.f,0.f,0.f,0.f};

  #pragma unroll 4
  for (int s = 0; s < 32; s++){
    int ko = s*32;
    short8v bh[2], bl[2];
    bh[0] = *(const short8v*)(bh0 + ko);
    bl[0] = *(const short8v*)(bl0 + ko);
    bh[1] = *(const short8v*)(bh1 + ko);
    bl[1] = *(const short8v*)(bl1 + ko);
    #pragma unroll
    for (int rt = 0; rt < 2; rt++){
      float4 a0 = *(const float4*)(ap[rt] + ko);
      float4 a1 = *(const float4*)(ap[rt] + ko + 4);
      float av[8] = {a0.x,a0.y,a0.z,a0.w,a1.x,a1.y,a1.z,a1.w};
      short8v ah, al;
      #pragma unroll
      for (int j = 0; j < 8; j++){
        unsigned bits = __float_as_uint(av[j]);
        ah[j] = (short)(bits >> 16);
        float lo = av[j] - __uint_as_float(bits & 0xFFFF0000u);
        al[j] = (short)(__float_as_uint(lo) >> 16);
      }
      #pragma unroll
      for (int ct = 0; ct < 2; ct++){
        acc[rt][ct] = __builtin_amdgcn_mfma_f32_16x16x32_bf16(ah, bh[ct], acc[rt][ct], 0, 0, 0);
        acc[rt][ct] = __builtin_amdgcn_mfma_f32_16x16x32_bf16(ah, bl[ct], acc[rt][ct], 0, 0, 0);
        acc[rt][ct] = __builtin_amdgcn_mfma_f32_16x16x32_bf16(al, bh[ct], acc[rt][ct], 0, 0, 0);
      }
    }
  }

  #pragma unroll
  for (int rt = 0; rt < 2; rt++){
    #pragma unroll
    for (int ct = 0; ct < 2; ct++){
      int t = ct*16 + rlo;
      if (t >= 25) continue;
      #pragma unroll
      for (int reg = 0; reg < 4; reg++){
        int rout = R0 + rt*16 + kg*4 + reg;
        if (rout < VOCAB)
          C[(size_t)t*VOCAB + rout] = acc[rt][ct][reg] + bias[rout];
      }
    }
  }
}

// ---------------- K_lstat: per (t, chunk) online max/argmax/sumexp ----------------
__global__ __launch_bounds__(256) void k_lstat(const float* __restrict__ C,
                                               float* __restrict__ pm,
                                               float* __restrict__ ps,
                                               int*   __restrict__ pa){
  __shared__ float sm[256], ss[256];
  __shared__ int   sa[256];
  int t = blockIdx.x, c = blockIdx.y, tid = threadIdx.x;
  int r0 = c*6283, r1 = min(r0 + 6283, VOCAB);
  const float* p = C + (size_t)t*VOCAB;
  float m = -3.4e38f, s = 0.f; int arg = r0;
  for (int r = r0 + tid; r < r1; r += 256){
    float x = p[r];
    if (x > m){ s = s*expf(m - x) + 1.f; m = x; arg = r; }
    else       s += expf(x - m);
  }
  sm[tid] = m; ss[tid] = s; sa[tid] = arg; __syncthreads();
  for (int st = 128; st > 0; st >>= 1){
    if (tid < st){
      float m1 = sm[tid], s1 = ss[tid]; int a1 = sa[tid];
      float m2 = sm[tid+st], s2 = ss[tid+st]; int a2 = sa[tid+st];
      if (m2 > m1){ sm[tid] = m2; ss[tid] = s2 + s1*expf(m1 - m2); sa[tid] = a2; }
      else if (m2 == m1){ ss[tid] = s1 + s2; sa[tid] = min(a1, a2); }
      else { ss[tid] = s1 + s2*expf(m2 - m1); }
    }
    __syncthreads();
  }
  if (tid == 0){ pm[t*8 + c] = sm[0]; ps[t*8 + c] = ss[0]; pa[t*8 + c] = sa[0]; }
}

// ---------------- K_lsub2: folds lfin; per-block redundant combine, then subtract ----------------
__global__ __launch_bounds__(256) void k_lsub2(float* __restrict__ C,
                                               const float* __restrict__ pm,
                                               const float* __restrict__ ps,
                                               const int* __restrict__ pa,
                                               float* __restrict__ out){
  int t = blockIdx.y;
  float M = pm[t*8], S = ps[t*8]; int A = pa[t*8];
  #pragma unroll
  for (int c = 1; c < 8; c++){
    float m2 = pm[t*8+c], s2 = ps[t*8+c]; int a2 = pa[t*8+c];
    if (m2 > M){ S = s2 + S*expf(M - m2); M = m2; A = a2; }
    else if (m2 == M){ S += s2; A = min(A, a2); }
    else S += s2*expf(m2 - M);
  }
  float Lg = logf(S) + M;
  int r = blockIdx.x*256 + threadIdx.x;
  if (r < VOCAB) C[(size_t)t*VOCAB + r] -= Lg;
  if (blockIdx.x == 0 && threadIdx.x == 0) out[t] = (float)A;
}

// ---------------- launch ----------------
extern "C" void kernel_launch(void* const* d_in, const int* in_sizes, int n_in,
                              void* d_out, int out_size, void* d_ws, size_t ws_size,
                              hipStream_t stream){
  const float* qw  = (const float*)d_in[0];
  const float* qv  = (const float*)d_in[1];
  const float* dv  = (const float*)d_in[2];
  const int*   ta  = (const int*)d_in[3];
  const float* emb = (const float*)d_in[4];
  const float* Wih = (const float*)d_in[5];
  const float* Whh = (const float*)d_in[6];
  const float* bih = (const float*)d_in[7];
  const float* bhh = (const float*)d_in[8];
  const float* Wq  = (const float*)d_in[9];
  const float* bq  = (const float*)d_in[10];
  const float* Wk  = (const float*)d_in[11];
  const float* bk  = (const float*)d_in[12];
  const float* av  = (const float*)d_in[13];
  const float* cW  = (const float*)d_in[14];
  const float* cb  = (const float*)d_in[15];
  const float* oW  = (const float*)d_in[16];
  const float* ob  = (const float*)d_in[17];
  float* out = (float*)d_out;
  float* ws  = (float*)d_ws;

  float* part  = ws;                 // 1048576 (live until attn1)
  float* ep    = ws + 1048576;       // 204800
  float* E     = ws + 1310720;       // 25600
  float* gib   = ws + 1336320;       // 3072
  float* gi    = ws + 1339392;       // 76800
  float* HC    = ws + 1416192;       // 51200
  float* Qt    = ws + 1467392;       // 25600
  float* VEC   = ws + 1492992;       // 25600
  unsigned* hx = (unsigned*)(ws + 1518592); // 51200
  float* pm    = ws + 1569792;       // 200
  float* ps    = ws + 1570048;       // 200
  int*   pa    = (int*)(ws + 1570304); // 200
  short* Bhi   = (short*)(ws + 1570816); // 25600 shorts
  short* Blo   = (short*)(ws + 1583616); // 25600 shorts

  k_pre_keys<<<1174, 256, 0, stream>>>(Wih, qv, bih, ta, emb, qw, Wk, gib, E, part, (uint4*)hx);
  k_gemm_s2<1024,16><<<768, 256, 0, stream>>>(Wih + 1024, 2048, E, 1024, gib, gi, 3072, 25, 0, nullptr, nullptr);
  k_gru8<<<128, 512, 0, stream>>>(Whh, bhh, gi, dv, HC, hx);
  k_gemm_s2<1024,16><<<256, 256, 0, stream>>>(Wq, 1024, HC, 2048, bq, Qt, 1024, 25, 0, nullptr, nullptr);
  k_attn1<<<dim3(25,32), 256, 0, stream>>>(part, bk, Qt, av, ep);
  k_attn2<<<dim3(25,2), 256, 0, stream>>>(ep, qw, HC);
  k_gemm_s2<2048,8><<<256, 256, 0, stream>>>(cW, 2048, HC, 2048, cb, VEC, 1024, 25, 1, Bhi, Blo);
  k_gemm_mfma3<<<393, 256, 0, stream>>>(oW, Bhi, Blo, ob, out + 25);
  k_lstat<<<dim3(25,8), 256, 0, stream>>>(out + 25, pm, ps, pa);
  k_lsub2<<<dim3(197,25), 256, 0, stream>>>(out + 25, pm, ps, pa, out);
}

// Round 23
// 349.962 us; speedup vs baseline: 1.0877x; 1.0371x over previous
//
#include <hip/hip_runtime.h>
#include <math.h>

#define VOCAB 50257
#define EMB 1024
#define HD 1024
#define TRK 1024
#define LQ 256
#define BND 25
#define SENT 0xAAAAAAAAu

typedef __attribute__((ext_vector_type(8))) short short8v;
typedef __attribute__((ext_vector_type(4))) float float4v;

// ---------------- helpers ----------------
__device__ __forceinline__ float wred(float s){
  #pragma unroll
  for (int m = 32; m >= 1; m >>= 1) s += __shfl_xor(s, m, 64);
  return s;
}

// ---------------- K_pre_keys: fused pre + keys + hx sentinel clear ----------------
__global__ __launch_bounds__(256) void k_pre_keys(const float* __restrict__ Wih,
                                                  const float* __restrict__ qv,
                                                  const float* __restrict__ bih,
                                                  const int*   __restrict__ ta,
                                                  const float* __restrict__ emb,
                                                  const float* __restrict__ qw,
                                                  const float* __restrict__ Wk,
                                                  float* __restrict__ gib,
                                                  float* __restrict__ E,
                                                  float* __restrict__ part,
                                                  uint4* __restrict__ hxc){
  __shared__ float qt[64*256];
  int b = blockIdx.x, tid = threadIdx.x;
  if (b >= 1124){
    hxc[(b - 1124)*256 + tid] = make_uint4(SENT, SENT, SENT, SENT);
    return;
  }
  if (b < 768){
    int w = tid >> 6, lane = tid & 63;
    int row = b*4 + w;
    const float* a = Wih + (size_t)row*2048;
    float s = 0.f;
    #pragma unroll
    for (int e = 0; e < 4; e++){
      int k = e*256 + lane*4;
      float4 av = *(const float4*)(a + k);
      float4 qr = *(const float4*)(qv + k);
      s += av.x*qr.x + av.y*qr.y + av.z*qr.z + av.w*qr.w;
    }
    s = wred(s);
    if (lane == 0) gib[row] = s + bih[row];
    return;
  }
  if (b < 868){
    int g = (b - 768)*256 + tid;
    int t = g >> 10, i = g & 1023;
    int idx = (t == 0) ? 0 : ta[t-1];
    E[g] = emb[(size_t)idx*EMB + i];
    return;
  }
  int b2 = b - 868;
  int jb = b2 & 63;
  int ks = b2 >> 6;
  int l = tid;
  float acc[16];
  #pragma unroll
  for (int j = 0; j < 16; j++) acc[j] = 0.f;

  for (int kt = 0; kt < 4; kt++){
    int kb = ks*256 + kt*64;
    __syncthreads();
    #pragma unroll
    for (int p = 0; p < 16; p++){
      int fidx = (p*256 + tid)*4;
      int kk = fidx & 63, ll = fidx >> 6;
      float4 v = *(const float4*)(qw + (size_t)ll*1024 + kb + kk);
      qt[(kk+0)*256 + (ll ^ ((kk+0)&31))] = v.x;
      qt[(kk+1)*256 + (ll ^ ((kk+1)&31))] = v.y;
      qt[(kk+2)*256 + (ll ^ ((kk+2)&31))] = v.z;
      qt[(kk+3)*256 + (ll ^ ((kk+3)&31))] = v.w;
    }
    __syncthreads();
    #pragma unroll
    for (int s = 0; s < 4; s++){
      float qr[16];
      #pragma unroll
      for (int q = 0; q < 16; q++){
        int k = s*16 + q;
        qr[q] = qt[k*256 + (l ^ (k&31))];
      }
      #pragma unroll
      for (int j = 0; j < 16; j++){
        const float* wr = Wk + (size_t)(jb*16 + j)*1024 + kb + s*16;
        #pragma unroll
        for (int q4 = 0; q4 < 4; q4++){
          float4 wv = *(const float4*)(wr + q4*4);
          acc[j] += qr[q4*4+0]*wv.x + qr[q4*4+1]*wv.y
                  + qr[q4*4+2]*wv.z + qr[q4*4+3]*wv.w;
        }
      }
    }
  }
  #pragma unroll
  for (int j = 0; j < 16; j++)
    part[((size_t)ks*1024 + jb*16 + j)*256 + l] = acc[j];
}

// ---------------- K_gemm_s2: skinny GEMM; optional bf16 hi/lo emit ----------------
template<int K, int NCH>
__global__ __launch_bounds__(256) void k_gemm_s2(const float* __restrict__ A, int lda,
                                                 const float* __restrict__ B, int ldb,
                                                 const float* __restrict__ bias,
                                                 float* __restrict__ C,
                                                 int R, int N, int act,
                                                 short* __restrict__ Bhi,
                                                 short* __restrict__ Blo){
  __shared__ float Bl[NCH*K];
  constexpr int KD4 = K/4;
  int tid = threadIdx.x, w = tid >> 6, lane = tid & 63;
  int row = blockIdx.x*4 + w;
  const float* a = A + (size_t)row*lda;
  float4 ar[K/256];
  #pragma unroll
  for (int e = 0; e < K/256; e++)
    ar[e] = *(const float4*)(a + e*256 + lane*4);
  float bs = bias[row];
  for (int c0 = 0; c0 < N; c0 += NCH){
    int nt = min(NCH, N - c0);
    __syncthreads();
    int total = nt*KD4;
    for (int i = tid; i < total; i += 256){
      int j = i/KD4, kk = i - j*KD4;
      *(float4*)&Bl[j*K + kk*4] = *(const float4*)(B + (size_t)(c0+j)*ldb + kk*4);
    }
    __syncthreads();
    for (int j = 0; j < nt; j++){
      float s = 0.f;
      #pragma unroll
      for (int e = 0; e < K/256; e++){
        float4 bv = *(const float4*)&Bl[j*K + e*256 + lane*4];
        s += ar[e].x*bv.x + ar[e].y*bv.y + ar[e].z*bv.z + ar[e].w*bv.w;
      }
      s = wred(s);
      if (lane == 0){
        float v = s + bs;
        if (act) v = tanhf(v);
        C[(size_t)(c0+j)*R + row] = v;
        if (Bhi){
          size_t idx = (size_t)(c0+j)*R + row;
          unsigned bits = __float_as_uint(v);
          Bhi[idx] = (short)(bits >> 16);
          float lo = v - __uint_as_float(bits & 0xFFFF0000u);
          Blo[idx] = (short)(__float_as_uint(lo) >> 16);
        }
      }
    }
  }
}

// ---------------- K_gru8: 25 steps; 128 blocks x 512 thr; 2-wave poll + backoff ----------------
__global__ __launch_bounds__(512, 1) void k_gru8(const float* __restrict__ Whh,
                                                 const float* __restrict__ bhh,
                                                 const float* __restrict__ gi,
                                                 const float* __restrict__ dv,
                                                 float* __restrict__ HC,
                                                 unsigned* __restrict__ hxu){
  __shared__ float Wl[24][1024];
  __shared__ float hbuf[1024];
  __shared__ float sres[24];
  int tid = threadIdx.x, w = tid >> 6, lane = tid & 63;
  int b = blockIdx.x;
  for (int i = tid; i < 6144; i += 512){
    int r = i >> 8, c = (i & 255)*4;
    int g = r >> 3, s = r & 7;
    *(float4*)&Wl[r][c] = *(const float4*)(Whh + (size_t)(g*1024 + b*8 + s)*1024 + c);
  }
  if (tid < 256)
    *(float4*)&hbuf[tid*4] = *(const float4*)(dv + tid*4);
  __syncthreads();

  for (int t = 0; t < BND; t++){
    float g0=0,g1=0,g2=0,bb0=0,bb1=0,bb2=0,hpown=0;
    if (tid < 8){
      int i = b*8 + tid;
      const float* gg = gi + (size_t)t*3072;
      g0 = gg[i]; g1 = gg[1024+i]; g2 = gg[2048+i];
      bb0 = bhh[i]; bb1 = bhh[1024+i]; bb2 = bhh[2048+i];
      hpown = hbuf[i];
    }
    float hv[16];
    #pragma unroll
    for (int e = 0; e < 4; e++){
      float4 v = *(const float4*)&hbuf[e*256 + lane*4];
      hv[e*4]=v.x; hv[e*4+1]=v.y; hv[e*4+2]=v.z; hv[e*4+3]=v.w;
    }
    #pragma unroll
    for (int j = 0; j < 3; j++){
      int r = w*3 + j;
      float a = 0.f;
      #pragma unroll
      for (int e = 0; e < 4; e++){
        float4 v = *(const float4*)&Wl[r][e*256 + lane*4];
        a += v.x*hv[e*4] + v.y*hv[e*4+1] + v.z*hv[e*4+2] + v.w*hv[e*4+3];
      }
      a = wred(a);
      if (lane == 0) sres[r] = a;
    }
    __syncthreads();
    if (tid < 8){
      int i = b*8 + tid;
      float ghr = sres[tid]      + bb0;
      float ghz = sres[8  + tid] + bb1;
      float ghn = sres[16 + tid] + bb2;
      float rr = 1.f/(1.f + expf(-(g0 + ghr)));
      float zz = 1.f/(1.f + expf(-(g1 + ghz)));
      float nn = tanhf(g2 + rr*ghn);
      float hnew = (1.f - zz)*nn + zz*hpown;
      HC[(size_t)t*2048 + i] = hnew;
      if (t < BND-1){
        union { float f; unsigned u; } cv; cv.f = hnew;
        if (cv.u == SENT) cv.u ^= 1u;
        __hip_atomic_store(hxu + (size_t)t*2048 + b*16 + tid, cv.u,
                           __ATOMIC_RELAXED, __HIP_MEMORY_SCOPE_AGENT);
      }
    }
    if (t == BND-1) break;
    if (w < 2){
      int blk = w*64 + lane;
      const unsigned* bp = hxu + (size_t)t*2048 + blk*16;
      unsigned d[8];
      for (;;){
        bool ok = true;
        #pragma unroll
        for (int j = 0; j < 8; j++){
          d[j] = __hip_atomic_load(bp + j, __ATOMIC_RELAXED, __HIP_MEMORY_SCOPE_AGENT);
          ok = ok && (d[j] != SENT);
        }
        if (ok) break;
        __builtin_amdgcn_s_sleep(1);
      }
      #pragma unroll
      for (int j = 0; j < 8; j++)
        hbuf[blk*8 + j] = __uint_as_float(d[j]);
    }
    __syncthreads();
  }
}

// ---------------- K_attn1: e partials; folds keys 4-way reduction ----------------
__global__ __launch_bounds__(256) void k_attn1(const float* __restrict__ part,
                                               const float* __restrict__ bk,
                                               const float* __restrict__ Qt,
                                               const float* __restrict__ av,
                                               float* __restrict__ epart){
  int t = blockIdx.x, jc = blockIdx.y;
  int l = threadIdx.x;
  const float* q = Qt + (size_t)t*1024;
  int j0 = jc*32;
  float acc = 0.f;
  #pragma unroll
  for (int u = 0; u < 8; u++){
    #pragma unroll
    for (int v = 0; v < 4; v++){
      int j = j0 + u*4 + v;
      float kv = part[(size_t)j*256 + l]
               + part[(size_t)(1024+j)*256 + l]
               + part[(size_t)(2048+j)*256 + l]
               + part[(size_t)(3072+j)*256 + l]
               + bk[j];
      acc += tanhf(kv + q[j]) * av[j];
    }
  }
  epart[((size_t)t*32 + jc)*256 + l] = acc;
}

// ---------------- K_attn2: softmax + ctx; grid (25,2) ----------------
__global__ __launch_bounds__(256) void k_attn2(const float* __restrict__ epart,
                                               const float* __restrict__ qw,
                                               float* __restrict__ HC){
  __shared__ float red[256];
  __shared__ float sw[256];
  int t = blockIdx.x, half = blockIdx.y, tid = threadIdx.x;
  float e = 0.f;
  for (int jc = 0; jc < 32; jc++) e += epart[((size_t)t*32 + jc)*256 + tid];
  red[tid] = e; __syncthreads();
  for (int s = 128; s > 0; s >>= 1){
    if (tid < s) red[tid] = fmaxf(red[tid], red[tid+s]);
    __syncthreads();
  }
  float m = red[0]; __syncthreads();
  float wv = expf(e - m);
  red[tid] = wv; __syncthreads();
  for (int s = 128; s > 0; s >>= 1){
    if (tid < s) red[tid] += red[tid+s];
    __syncthreads();
  }
  float inv = 1.f/red[0];
  sw[tid] = wv*inv; __syncthreads();
  float2 c = make_float2(0.f, 0.f);
  const float* qp = qw + half*512 + tid*2;
  for (int ll = 0; ll < 256; ll++){
    float wl = sw[ll];
    float2 v = *(const float2*)(qp + (size_t)ll*1024);
    c.x += wl*v.x; c.y += wl*v.y;
  }
  *(float2*)(HC + (size_t)t*2048 + 1024 + half*512 + tid*2) = c;
}

// ---------------- K_gemm_mfma5: mfma3 + explicit double-buffer prefetch ----------------
// 393 blocks x 256 thr, r=2 rowtiles x 2 coltiles. Slice s+1's 8 loads (4 B short8v
// + 4 A float4) issue BEFORE slice s's convert+12 MFMA -> 2x outstanding loads per
// wave (the grid caps waves/SIMD at ~1.5; latency hiding must come from in-wave MLP).
// VGPR ~100 < 256 budget at (256,1). Same 3-pass numerics as mfma3.
__global__ __launch_bounds__(256, 1) void k_gemm_mfma5(const float* __restrict__ A,
                                                       const short* __restrict__ Bhi,
                                                       const short* __restrict__ Blo,
                                                       const float* __restrict__ bias,
                                                       float* __restrict__ C){
  int tid = threadIdx.x, lane = tid & 63, w = tid >> 6;
  int rlo = lane & 15, kg = lane >> 4;
  int R0 = blockIdx.x*128 + w*32;

  const float* ap[2];
  #pragma unroll
  for (int rt = 0; rt < 2; rt++){
    int row = R0 + rt*16 + rlo;
    if (row >= VOCAB) row = VOCAB-1;
    ap[rt] = A + (size_t)row*1024 + kg*8;
  }
  int t0 = rlo;
  int t1 = 16 + rlo; if (t1 > 24) t1 = 24;
  const short* bh0 = Bhi + t0*1024 + kg*8;
  const short* bl0 = Blo + t0*1024 + kg*8;
  const short* bh1 = Bhi + t1*1024 + kg*8;
  const short* bl1 = Blo + t1*1024 + kg*8;

  float4v acc[2][2];
  #pragma unroll
  for (int rt = 0; rt < 2; rt++)
    #pragma unroll
    for (int ct = 0; ct < 2; ct++)
      acc[rt][ct] = (float4v){0.f,0.f,0.f,0.f};

  // pipeline buffers: current (c) and next (n)
  short8v bhc[2], blc[2], bhn[2], bln[2];
  float4 a0c[2], a1c[2], a0n[2], a1n[2];

  bhc[0] = *(const short8v*)(bh0);
  blc[0] = *(const short8v*)(bl0);
  bhc[1] = *(const short8v*)(bh1);
  blc[1] = *(const short8v*)(bl1);
  #pragma unroll
  for (int rt = 0; rt < 2; rt++){
    a0c[rt] = *(const float4*)(ap[rt] + 0);
    a1c[rt] = *(const float4*)(ap[rt] + 4);
  }

  #pragma unroll 1
  for (int s = 0; s < 32; s++){
    // issue next-slice loads first (overlap with this slice's convert+MFMA)
    if (s + 1 < 32){
      int ko = (s+1)*32;
      bhn[0] = *(const short8v*)(bh0 + ko);
      bln[0] = *(const short8v*)(bl0 + ko);
      bhn[1] = *(const short8v*)(bh1 + ko);
      bln[1] = *(const short8v*)(bl1 + ko);
      #pragma unroll
      for (int rt = 0; rt < 2; rt++){
        a0n[rt] = *(const float4*)(ap[rt] + ko);
        a1n[rt] = *(const float4*)(ap[rt] + ko + 4);
      }
    }
    #pragma unroll
    for (int rt = 0; rt < 2; rt++){
      float av[8] = {a0c[rt].x,a0c[rt].y,a0c[rt].z,a0c[rt].w,
                     a1c[rt].x,a1c[rt].y,a1c[rt].z,a1c[rt].w};
      short8v ah, al;
      #pragma unroll
      for (int j = 0; j < 8; j++){
        unsigned bits = __float_as_uint(av[j]);
        ah[j] = (short)(bits >> 16);
        float lo = av[j] - __uint_as_float(bits & 0xFFFF0000u);
        al[j] = (short)(__float_as_uint(lo) >> 16);
      }
      #pragma unroll
      for (int ct = 0; ct < 2; ct++){
        acc[rt][ct] = __builtin_amdgcn_mfma_f32_16x16x32_bf16(ah, bhc[ct], acc[rt][ct], 0, 0, 0);
        acc[rt][ct] = __builtin_amdgcn_mfma_f32_16x16x32_bf16(ah, blc[ct], acc[rt][ct], 0, 0, 0);
        acc[rt][ct] = __builtin_amdgcn_mfma_f32_16x16x32_bf16(al, bhc[ct], acc[rt][ct], 0, 0, 0);
      }
    }
    bhc[0] = bhn[0]; blc[0] = bln[0]; bhc[1] = bhn[1]; blc[1] = bln[1];
    #pragma unroll
    for (int rt = 0; rt < 2; rt++){
      a0c[rt] = a0n[rt]; a1c[rt] = a1n[rt];
    }
  }

  #pragma unroll
  for (int rt = 0; rt < 2; rt++){
    #pragma unroll
    for (int ct = 0; ct < 2; ct++){
      int t = ct*16 + rlo;
      if (t >= 25) continue;
      #pragma unroll
      for (int reg = 0; reg < 4; reg++){
        int rout = R0 + rt*16 + kg*4 + reg;
        if (rout < VOCAB)
          C[(size_t)t*VOCAB + rout] = acc[rt][ct][reg] + bias[rout];
      }
    }
  }
}

// ---------------- K_lstat: per (t, chunk) online max/argmax/sumexp ----------------
__global__ __launch_bounds__(256) void k_lstat(const float* __restrict__ C,
                                               float* __restrict__ pm,
                                               float* __restrict__ ps,
                                               int*   __restrict__ pa){
  __shared__ float sm[256], ss[256];
  __shared__ int   sa[256];
  int t = blockIdx.x, c = blockIdx.y, tid = threadIdx.x;
  int r0 = c*6283, r1 = min(r0 + 6283, VOCAB);
  const float* p = C + (size_t)t*VOCAB;
  float m = -3.4e38f, s = 0.f; int arg = r0;
  for (int r = r0 + tid; r < r1; r += 256){
    float x = p[r];
    if (x > m){ s = s*expf(m - x) + 1.f; m = x; arg = r; }
    else       s += expf(x - m);
  }
  sm[tid] = m; ss[tid] = s; sa[tid] = arg; __syncthreads();
  for (int st = 128; st > 0; st >>= 1){
    if (tid < st){
      float m1 = sm[tid], s1 = ss[tid]; int a1 = sa[tid];
      float m2 = sm[tid+st], s2 = ss[tid+st]; int a2 = sa[tid+st];
      if (m2 > m1){ sm[tid] = m2; ss[tid] = s2 + s1*expf(m1 - m2); sa[tid] = a2; }
      else if (m2 == m1){ ss[tid] = s1 + s2; sa[tid] = min(a1, a2); }
      else { ss[tid] = s1 + s2*expf(m2 - m1); }
    }
    __syncthreads();
  }
  if (tid == 0){ pm[t*8 + c] = sm[0]; ps[t*8 + c] = ss[0]; pa[t*8 + c] = sa[0]; }
}

// ---------------- K_lsub2: folds lfin; per-block redundant combine, then subtract ----------------
__global__ __launch_bounds__(256) void k_lsub2(float* __restrict__ C,
                                               const float* __restrict__ pm,
                                               const float* __restrict__ ps,
                                               const int* __restrict__ pa,
                                               float* __restrict__ out){
  int t = blockIdx.y;
  float M = pm[t*8], S = ps[t*8]; int A = pa[t*8];
  #pragma unroll
  for (int c = 1; c < 8; c++){
    float m2 = pm[t*8+c], s2 = ps[t*8+c]; int a2 = pa[t*8+c];
    if (m2 > M){ S = s2 + S*expf(M - m2); M = m2; A = a2; }
    else if (m2 == M){ S += s2; A = min(A, a2); }
    else S += s2*expf(m2 - M);
  }
  float Lg = logf(S) + M;
  int r = blockIdx.x*256 + threadIdx.x;
  if (r < VOCAB) C[(size_t)t*VOCAB + r] -= Lg;
  if (blockIdx.x == 0 && threadIdx.x == 0) out[t] = (float)A;
}

// ---------------- launch ----------------
extern "C" void kernel_launch(void* const* d_in, const int* in_sizes, int n_in,
                              void* d_out, int out_size, void* d_ws, size_t ws_size,
                              hipStream_t stream){
  const float* qw  = (const float*)d_in[0];
  const float* qv  = (const float*)d_in[1];
  const float* dv  = (const float*)d_in[2];
  const int*   ta  = (const int*)d_in[3];
  const float* emb = (const float*)d_in[4];
  const float* Wih = (const float*)d_in[5];
  const float* Whh = (const float*)d_in[6];
  const float* bih = (const float*)d_in[7];
  const float* bhh = (const float*)d_in[8];
  const float* Wq  = (const float*)d_in[9];
  const float* bq  = (const float*)d_in[10];
  const float* Wk  = (const float*)d_in[11];
  const float* bk  = (const float*)d_in[12];
  const float* av  = (const float*)d_in[13];
  const float* cW  = (const float*)d_in[14];
  const float* cb  = (const float*)d_in[15];
  const float* oW  = (const float*)d_in[16];
  const float* ob  = (const float*)d_in[17];
  float* out = (float*)d_out;
  float* ws  = (float*)d_ws;

  float* part  = ws;                 // 1048576 (live until attn1)
  float* ep    = ws + 1048576;       // 204800
  float* E     = ws + 1310720;       // 25600
  float* gib   = ws + 1336320;       // 3072
  float* gi    = ws + 1339392;       // 76800
  float* HC    = ws + 1416192;       // 51200
  float* Qt    = ws + 1467392;       // 25600
  float* VEC   = ws + 1492992;       // 25600
  unsigned* hx = (unsigned*)(ws + 1518592); // 51200
  float* pm    = ws + 1569792;       // 200
  float* ps    = ws + 1570048;       // 200
  int*   pa    = (int*)(ws + 1570304); // 200
  short* Bhi   = (short*)(ws + 1570816); // 25600 shorts
  short* Blo   = (short*)(ws + 1583616); // 25600 shorts

  k_pre_keys<<<1174, 256, 0, stream>>>(Wih, qv, bih, ta, emb, qw, Wk, gib, E, part, (uint4*)hx);
  k_gemm_s2<1024,16><<<768, 256, 0, stream>>>(Wih + 1024, 2048, E, 1024, gib, gi, 3072, 25, 0, nullptr, nullptr);
  k_gru8<<<128, 512, 0, stream>>>(Whh, bhh, gi, dv, HC, hx);
  k_gemm_s2<1024,16><<<256, 256, 0, stream>>>(Wq, 1024, HC, 2048, bq, Qt, 1024, 25, 0, nullptr, nullptr);
  k_attn1<<<dim3(25,32), 256, 0, stream>>>(part, bk, Qt, av, ep);
  k_attn2<<<dim3(25,2), 256, 0, stream>>>(ep, qw, HC);
  k_gemm_s2<2048,8><<<256, 256, 0, stream>>>(cW, 2048, HC, 2048, cb, VEC, 1024, 25, 1, Bhi, Blo);
  k_gemm_mfma5<<<393, 256, 0, stream>>>(oW, Bhi, Blo, ob, out + 25);
  k_lstat<<<dim3(25,8), 256, 0, stream>>>(out + 25, pm, ps, pa);
  k_lsub2<<<dim3(197,25), 256, 0, stream>>>(out + 25, pm, ps, pa, out);
}